// Round 5
// baseline (11121.456 us; speedup 1.0000x reference)
//
#include <hip/hip_runtime.h>
#include <hip/hip_bf16.h>
#include <stdint.h>

typedef __bf16 bf16_t;
typedef __attribute__((ext_vector_type(8))) __bf16 bf16x8;
typedef __attribute__((ext_vector_type(4))) float f32x4;

#define B_N 2048
#define T_N 96
#define I_N 64
#define H_N 1024
#define O_N 256
#define KTOT 1088   /* H + I */
#define NG   4096   /* 4*H  */

// ---------- helpers ----------
__device__ __forceinline__ void gload16(const void* g, void* l) {
  // global -> LDS direct, 16B per lane. LDS dest is wave-uniform base
  // (HW adds lane*16). Global source IS per-lane -> we pre-swizzle it.
  __builtin_amdgcn_global_load_lds(
      (const __attribute__((address_space(1))) uint32_t*)(uintptr_t)g,
      (__attribute__((address_space(3))) uint32_t*)(uintptr_t)l,
      16, 0, 0);
}

__device__ __forceinline__ float sigmoid_(float x) {
  return 1.0f / (1.0f + __expf(-x));
}
__device__ __forceinline__ float tanh_(float x) {
  float ax = fabsf(x);
  float e  = __expf(-2.0f * ax);     // (0,1], never overflows
  float t  = (1.0f - e) / (1.0f + e);
  return copysignf(t, x);
}

// ---------- prep kernels ----------
// Bmat row rr = 4*j + gate (gate-interleaved: the 4 gates of unit j adjacent)
__global__ void prep_weights(const float* __restrict__ Wi_h, const float* __restrict__ Wf_h,
                             const float* __restrict__ Wm_h, const float* __restrict__ Wo_h,
                             const float* __restrict__ Wi_x, const float* __restrict__ Wf_x,
                             const float* __restrict__ Wm_x, const float* __restrict__ Wo_x,
                             bf16_t* __restrict__ Bmat) {
  int idx = blockIdx.x * blockDim.x + threadIdx.x;
  const int total = NG * KTOT;
  if (idx >= total) return;
  int rr = idx / KTOT;
  int k  = idx - rr * KTOT;
  int j    = rr >> 2;       // unit
  int gate = rr & 3;        // 0:i 1:f 2:m 3:o
  const float* Wh[4] = {Wi_h, Wf_h, Wm_h, Wo_h};
  const float* Wx[4] = {Wi_x, Wf_x, Wm_x, Wo_x};
  float v = (k < H_N) ? Wh[gate][j * H_N + k] : Wx[gate][j * I_N + (k - H_N)];
  Bmat[idx] = (bf16_t)v;
}

__global__ void prep_misc(const float* __restrict__ bi, const float* __restrict__ bf_,
                          const float* __restrict__ bm, const float* __restrict__ bo,
                          const float* __restrict__ Wout, float* __restrict__ bbI,
                          bf16_t* __restrict__ Wout_b) {
  int idx = blockIdx.x * blockDim.x + threadIdx.x;
  if (idx < NG) {
    int j = idx >> 2, gate = idx & 3;
    const float* bp[4] = {bi, bf_, bm, bo};
    bbI[idx] = bp[gate][j];
  }
  if (idx < O_N * H_N) Wout_b[idx] = (bf16_t)Wout[idx];
}

__global__ void prep_seq(const float4* __restrict__ seq4, bf16_t* __restrict__ seqb,
                         bf16_t* __restrict__ h0, float* __restrict__ c0,
                         int* __restrict__ ctr) {
  int idx = blockIdx.x * blockDim.x + threadIdx.x;
  const int n4 = (B_N * T_N * I_N) / 4;
  if (idx < n4) {
    float4 v = seq4[idx];
    union { bf16_t b[4]; uint2 u; } pk;
    pk.b[0] = (bf16_t)v.x; pk.b[1] = (bf16_t)v.y;
    pk.b[2] = (bf16_t)v.z; pk.b[3] = (bf16_t)v.w;
    *reinterpret_cast<uint2*>(seqb + (size_t)idx * 4) = pk.u;
  }
  if (idx < B_N * H_N) { h0[idx] = (bf16_t)0.0f; c0[idx] = 0.0f; }
  if (idx < T_N * 16) ctr[idx] = 0;   // group-barrier counters, per launch
}

// Block geometry shared by both LSTM kernels:
// bid 0..511 -> bx = bid>>5 (batch group, 128 rows), by = bid&31 with
// XCD grouping (4 consecutive by per XCD for weight-slab L2 locality).
// Tile: 128 batch rows x 128 gate cols (32 units x 4 gates, interleaved).
// LDS: A bufs [0,16K)[16K,32K); B bufs [32K,48K)[48K,64K).  Total 64 KB.
// Epilogue overlays smem[0..33792) as float[64][132], two halves.

// ---------- persistent fused LSTM (all 96 steps; cooperative) ----------
__global__ __launch_bounds__(256, 2) void lstm_all(
    const bf16_t* __restrict__ Bmat,   // [4H][KTOT], row = 4*unit+gate
    const float*  __restrict__ bbI,    // [4H], idx = 4*unit+gate
    const bf16_t* __restrict__ seqb,   // [B][T][I]
    bf16_t* __restrict__ hbuf0,        // [B][H]  (zeroed: h_-1)
    bf16_t* __restrict__ hbuf1,        // [B][H]
    int* __restrict__ ctr) {           // [T][16]
  __shared__ char smem[65536];

  const int tid  = threadIdx.x;
  const int wid  = tid >> 6;
  const int lane = tid & 63;

  const int bid  = blockIdx.x;          // 0..511
  const int low5 = bid & 31;
  const int bx   = bid >> 5;                      // 0..15
  const int by   = (low5 & 7) * 4 + (low5 >> 3);  // 0..31

  const int bm0   = bx * 128;          // batch-row base
  const int n0    = by * 128;          // Bmat row base (contiguous slab)
  const int jbase = by * 32;           // unit base

  const int wr = wid >> 1, wc = wid & 1;   // 2M x 2N waves, 64x64 each
  const int lrow = lane & 15;

  const int srow = tid >> 3;                     // 0..31
  const int cs   = ((tid & 7) ^ (srow & 7)) * 8; // swizzled source chunk

  float c_reg[16];
#pragma unroll
  for (int p = 0; p < 16; ++p) c_reg[p] = 0.0f;

#pragma unroll 1
  for (int t = 0; t < T_N; ++t) {
    const bf16_t* h_in  = (t & 1) ? hbuf1 : hbuf0;
    bf16_t*       h_out = (t & 1) ? hbuf0 : hbuf1;

    f32x4 acc[4][4];
#pragma unroll
    for (int m = 0; m < 4; ++m)
#pragma unroll
      for (int n = 0; n < 4; ++n)
#pragma unroll
        for (int e = 0; e < 4; ++e) acc[m][n][e] = 0.0f;

    auto stage = [&](int b, int s) {
      char* Ab = smem + b * 16384;
      char* Bb = smem + 32768 + b * 16384;
      if (s < 16) {
        const int k0 = s * 64;
#pragma unroll
        for (int it = 0; it < 4; ++it)
          gload16(h_in + (size_t)(bm0 + it * 32 + srow) * H_N + k0 + cs,
                  Ab + it * 4096 + wid * 1024);
#pragma unroll
        for (int it = 0; it < 4; ++it)
          gload16(Bmat + (size_t)(n0 + it * 32 + srow) * KTOT + k0 + cs,
                  Bb + it * 4096 + wid * 1024);
      } else {
#pragma unroll
        for (int it = 0; it < 4; ++it)
          gload16(seqb + (size_t)(bm0 + it * 32 + srow) * (T_N * I_N) + t * I_N + cs,
                  Ab + it * 4096 + wid * 1024);
#pragma unroll
        for (int it = 0; it < 4; ++it)
          gload16(Bmat + (size_t)(n0 + it * 32 + srow) * KTOT + H_N + cs,
                  Bb + it * 4096 + wid * 1024);
      }
    };

    stage(0, 0);
    __syncthreads();

    int cur = 0;
    for (int kt = 0; kt < 17; ++kt) {
      if (kt < 16) stage(cur ^ 1, kt + 1);   // issue next-tile loads first

      const bf16_t* Abuf = (const bf16_t*)(smem + cur * 16384);
      const bf16_t* Bbuf = (const bf16_t*)(smem + 32768 + cur * 16384);
#pragma unroll
      for (int kh = 0; kh < 2; ++kh) {
        const int cc = (lane >> 4) + kh * 4;          // data chunk 0..7
        const int so = ((cc ^ (lrow & 7)) << 3);      // swizzled slot
        bf16x8 aq[4], bq[4];
#pragma unroll
        for (int m = 0; m < 4; ++m)
          aq[m] = *(const bf16x8*)(Abuf + (size_t)(wr * 64 + m * 16 + lrow) * 64 + so);
#pragma unroll
        for (int n = 0; n < 4; ++n)
          bq[n] = *(const bf16x8*)(Bbuf + (size_t)(wc * 64 + n * 16 + lrow) * 64 + so);
#pragma unroll
        for (int m = 0; m < 4; ++m)
#pragma unroll
          for (int n = 0; n < 4; ++n)
            acc[m][n] = __builtin_amdgcn_mfma_f32_16x16x32_bf16(aq[m], bq[n], acc[m][n], 0, 0, 0);
      }
      __syncthreads();   // next tile landed + all reads of cur done
      cur ^= 1;
    }

    // ---- two-half epilogue (overlay float[64][132] = 33792 B) ----
    float* g_lds = (float*)smem;
#pragma unroll 1
    for (int half = 0; half < 2; ++half) {
      if (wr == half) {
#pragma unroll
        for (int m = 0; m < 4; ++m)
#pragma unroll
          for (int n = 0; n < 4; ++n) {
            int r0 = m * 16 + (lane >> 4) * 4;
            int c  = wc * 64 + n * 16 + lrow;
#pragma unroll
            for (int e = 0; e < 4; ++e) g_lds[(size_t)(r0 + e) * 132 + c] = acc[m][n][e];
          }
      }
      __syncthreads();
#pragma unroll
      for (int p = 0; p < 8; ++p) {
        int idx = p * 256 + tid;       // 64 rows x 32 units
        int row = idx >> 5;
        int u   = idx & 31;
        float4 gv  = *(const float4*)&g_lds[(size_t)row * 132 + 4 * u];
        float4 bb4 = *(const float4*)&bbI[n0 + 4 * u];
        float i_ = sigmoid_(gv.x + bb4.x);
        float f_ = sigmoid_(gv.y + bb4.y);
        float m_ = tanh_(gv.z + bb4.z);
        float o_ = sigmoid_(gv.w + bb4.w);
        int cp = half * 8 + p;
        float cn = f_ * c_reg[cp] + i_ * m_;
        c_reg[cp] = cn;
        h_out[(size_t)(bm0 + half * 64 + row) * H_N + jbase + u] =
            (bf16_t)(o_ * tanh_(cn));
      }
      __syncthreads();   // reads done before next half's writes / next stage
    }

    // ---- bx-group barrier (32 blocks share these batch rows) ----
    if (t < T_N - 1) {
      __threadfence();          // release: flush h_out device-wide
      __syncthreads();
      if (tid == 0) {
        int* cp = ctr + t * 16 + bx;
        __hip_atomic_fetch_add(cp, 1, __ATOMIC_RELEASE, __HIP_MEMORY_SCOPE_AGENT);
        while (__hip_atomic_load(cp, __ATOMIC_ACQUIRE, __HIP_MEMORY_SCOPE_AGENT) < 32)
          __builtin_amdgcn_s_sleep(4);
      }
      __syncthreads();
      __threadfence();          // acquire: invalidate stale cached h lines
    }
  }
}

// ---------- fallback: one step per kernel (c in global) ----------
__global__ __launch_bounds__(256, 2) void lstm_step(
    const bf16_t* __restrict__ Bmat, const float* __restrict__ bbI,
    const bf16_t* __restrict__ seqb, const bf16_t* __restrict__ h_in,
    bf16_t* __restrict__ h_out, float* __restrict__ c_buf, int t) {
  __shared__ char smem[65536];

  const int tid  = threadIdx.x;
  const int wid  = tid >> 6;
  const int lane = tid & 63;

  const int bid  = blockIdx.x;
  const int low5 = bid & 31;
  const int bx   = bid >> 5;
  const int by   = (low5 & 7) * 4 + (low5 >> 3);

  const int bm0   = bx * 128;
  const int n0    = by * 128;
  const int jbase = by * 32;

  const int wr = wid >> 1, wc = wid & 1;
  const int lrow = lane & 15;

  const int srow = tid >> 3;
  const int cs   = ((tid & 7) ^ (srow & 7)) * 8;

  f32x4 acc[4][4];
#pragma unroll
  for (int m = 0; m < 4; ++m)
#pragma unroll
    for (int n = 0; n < 4; ++n)
#pragma unroll
      for (int e = 0; e < 4; ++e) acc[m][n][e] = 0.0f;

  auto stage = [&](int b, int s) {
    char* Ab = smem + b * 16384;
    char* Bb = smem + 32768 + b * 16384;
    if (s < 16) {
      const int k0 = s * 64;
#pragma unroll
      for (int it = 0; it < 4; ++it)
        gload16(h_in + (size_t)(bm0 + it * 32 + srow) * H_N + k0 + cs,
                Ab + it * 4096 + wid * 1024);
#pragma unroll
      for (int it = 0; it < 4; ++it)
        gload16(Bmat + (size_t)(n0 + it * 32 + srow) * KTOT + k0 + cs,
                Bb + it * 4096 + wid * 1024);
    } else {
#pragma unroll
      for (int it = 0; it < 4; ++it)
        gload16(seqb + (size_t)(bm0 + it * 32 + srow) * (T_N * I_N) + t * I_N + cs,
                Ab + it * 4096 + wid * 1024);
#pragma unroll
      for (int it = 0; it < 4; ++it)
        gload16(Bmat + (size_t)(n0 + it * 32 + srow) * KTOT + H_N + cs,
                Bb + it * 4096 + wid * 1024);
    }
  };

  stage(0, 0);
  __syncthreads();

  int cur = 0;
  for (int kt = 0; kt < 17; ++kt) {
    if (kt < 16) stage(cur ^ 1, kt + 1);

    const bf16_t* Abuf = (const bf16_t*)(smem + cur * 16384);
    const bf16_t* Bbuf = (const bf16_t*)(smem + 32768 + cur * 16384);
#pragma unroll
    for (int kh = 0; kh < 2; ++kh) {
      const int cc = (lane >> 4) + kh * 4;
      const int so = ((cc ^ (lrow & 7)) << 3);
      bf16x8 aq[4], bq[4];
#pragma unroll
      for (int m = 0; m < 4; ++m)
        aq[m] = *(const bf16x8*)(Abuf + (size_t)(wr * 64 + m * 16 + lrow) * 64 + so);
#pragma unroll
      for (int n = 0; n < 4; ++n)
        bq[n] = *(const bf16x8*)(Bbuf + (size_t)(wc * 64 + n * 16 + lrow) * 64 + so);
#pragma unroll
      for (int m = 0; m < 4; ++m)
#pragma unroll
        for (int n = 0; n < 4; ++n)
          acc[m][n] = __builtin_amdgcn_mfma_f32_16x16x32_bf16(aq[m], bq[n], acc[m][n], 0, 0, 0);
    }
    __syncthreads();
    cur ^= 1;
  }

  float* g_lds = (float*)smem;
#pragma unroll 1
  for (int half = 0; half < 2; ++half) {
    if (wr == half) {
#pragma unroll
      for (int m = 0; m < 4; ++m)
#pragma unroll
        for (int n = 0; n < 4; ++n) {
          int r0 = m * 16 + (lane >> 4) * 4;
          int c  = wc * 64 + n * 16 + lrow;
#pragma unroll
          for (int e = 0; e < 4; ++e) g_lds[(size_t)(r0 + e) * 132 + c] = acc[m][n][e];
        }
    }
    __syncthreads();
#pragma unroll
    for (int p = 0; p < 8; ++p) {
      int idx = p * 256 + tid;
      int row = idx >> 5;
      int u   = idx & 31;
      float4 gv  = *(const float4*)&g_lds[(size_t)row * 132 + 4 * u];
      float4 bb4 = *(const float4*)&bbI[n0 + 4 * u];
      float i_ = sigmoid_(gv.x + bb4.x);
      float f_ = sigmoid_(gv.y + bb4.y);
      float m_ = tanh_(gv.z + bb4.z);
      float o_ = sigmoid_(gv.w + bb4.w);
      int gi = (bm0 + half * 64 + row) * H_N + jbase + u;
      float cn = f_ * c_buf[gi] + i_ * m_;
      c_buf[gi] = cn;
      h_out[gi] = (bf16_t)(o_ * tanh_(cn));
    }
    __syncthreads();
  }
}

// ---------- final projection: out = h_last @ Wout^T + bout ----------
__global__ __launch_bounds__(256, 2) void out_gemm(
    const bf16_t* __restrict__ h,     // [B][H]
    const bf16_t* __restrict__ Wb,    // [O][H]
    const float*  __restrict__ bout,  // [O]
    float* __restrict__ out) {        // [B][O]
  __shared__ char smem[16384 + 8192];
  bf16_t* A_lds = (bf16_t*)smem;            // [128][64]
  bf16_t* B_lds = (bf16_t*)(smem + 16384);  // [64][64]

  const int tid = threadIdx.x, wid = tid >> 6, lane = tid & 63;
  const int bm0 = blockIdx.x * 128;
  const int n0  = blockIdx.y * 64;
  const int wr = wid >> 1, wc = wid & 1;    // wave: 64 rows x 32 cols

  f32x4 acc[4][2];
#pragma unroll
  for (int m = 0; m < 4; ++m)
#pragma unroll
    for (int n = 0; n < 2; ++n)
#pragma unroll
      for (int e = 0; e < 4; ++e) acc[m][n][e] = 0.0f;

  const int srow = tid >> 3;
  const int scol = (tid & 7) * 8;

  for (int kt = 0; kt < 16; ++kt) {
    const int k0 = kt * 64;
#pragma unroll
    for (int it = 0; it < 4; ++it) {
      const bf16_t* gp = h + (size_t)(bm0 + it * 32 + srow) * H_N + k0 + scol;
      gload16(gp, (char*)A_lds + (size_t)(it * 2048 + wid * 512) * 2);
    }
#pragma unroll
    for (int it = 0; it < 2; ++it) {
      const bf16_t* gp = Wb + (size_t)(n0 + it * 32 + srow) * H_N + k0 + scol;
      gload16(gp, (char*)B_lds + (size_t)(it * 2048 + wid * 512) * 2);
    }
    __syncthreads();

    const int lrow = lane & 15;
#pragma unroll
    for (int kk = 0; kk < 64; kk += 32) {
      const int lk = (lane >> 4) * 8 + kk;
      bf16x8 aq[4], bq[2];
#pragma unroll
      for (int m = 0; m < 4; ++m)
        aq[m] = *(const bf16x8*)(A_lds + (size_t)(wr * 64 + m * 16 + lrow) * 64 + lk);
#pragma unroll
      for (int n = 0; n < 2; ++n)
        bq[n] = *(const bf16x8*)(B_lds + (size_t)(wc * 32 + n * 16 + lrow) * 64 + lk);
#pragma unroll
      for (int m = 0; m < 4; ++m)
#pragma unroll
        for (int n = 0; n < 2; ++n)
          acc[m][n] = __builtin_amdgcn_mfma_f32_16x16x32_bf16(aq[m], bq[n], acc[m][n], 0, 0, 0);
    }
    __syncthreads();
  }

#pragma unroll
  for (int m = 0; m < 4; ++m)
#pragma unroll
    for (int n = 0; n < 2; ++n)
#pragma unroll
      for (int e = 0; e < 4; ++e) {
        int row = bm0 + wr * 64 + m * 16 + (lane >> 4) * 4 + e;
        int col = n0 + wc * 32 + n * 16 + (lane & 15);
        out[(size_t)row * O_N + col] = acc[m][n][e] + bout[col];
      }
}

// ---------- launch ----------
extern "C" void kernel_launch(void* const* d_in, const int* in_sizes, int n_in,
                              void* d_out, int out_size, void* d_ws, size_t ws_size,
                              hipStream_t stream) {
  const float* seq  = (const float*)d_in[0];
  const float* Wf_x = (const float*)d_in[1];
  const float* bf_  = (const float*)d_in[2];
  const float* Wf_h = (const float*)d_in[3];
  const float* Wi_x = (const float*)d_in[4];
  const float* bi   = (const float*)d_in[5];
  const float* Wi_h = (const float*)d_in[6];
  const float* Wm_x = (const float*)d_in[7];
  const float* bm   = (const float*)d_in[8];
  const float* Wm_h = (const float*)d_in[9];
  const float* Wo_x = (const float*)d_in[10];
  const float* bo   = (const float*)d_in[11];
  const float* Wo_h = (const float*)d_in[12];
  const float* Wout = (const float*)d_in[13];
  const float* bout = (const float*)d_in[14];
  float* out = (float*)d_out;

  char* ws = (char*)d_ws;
  size_t off = 0;
  auto alloc = [&](size_t bytes) -> void* {
    void* p = ws + off;
    off = (off + bytes + 255) & ~(size_t)255;
    return p;
  };
  bf16_t* Bmat   = (bf16_t*)alloc((size_t)NG * KTOT * 2);       // 8.9 MB
  float*  bb_all = (float*) alloc((size_t)NG * 4);              // 16 KB
  bf16_t* Woutb  = (bf16_t*)alloc((size_t)O_N * H_N * 2);       // 512 KB
  bf16_t* seqb   = (bf16_t*)alloc((size_t)B_N * T_N * I_N * 2); // 24 MB
  bf16_t* hbuf0  = (bf16_t*)alloc((size_t)B_N * H_N * 2);       // 4 MB
  bf16_t* hbuf1  = (bf16_t*)alloc((size_t)B_N * H_N * 2);       // 4 MB
  float*  cbuf   = (float*) alloc((size_t)B_N * H_N * 4);       // 8 MB
  int*    ctr    = (int*)   alloc((size_t)T_N * 16 * 4);        // 6 KB

  prep_weights<<<(NG * KTOT + 255) / 256, 256, 0, stream>>>(
      Wi_h, Wf_h, Wm_h, Wo_h, Wi_x, Wf_x, Wm_x, Wo_x, Bmat);
  prep_misc<<<(O_N * H_N + 255) / 256, 256, 0, stream>>>(
      bi, bf_, bm, bo, Wout, bb_all, Woutb);
  prep_seq<<<((B_N * T_N * I_N / 4) + 255) / 256, 256, 0, stream>>>(
      (const float4*)seq, seqb, hbuf0, cbuf, ctr);

  // Try persistent cooperative LSTM (512 blocks x 256 thr, 2/CU co-resident).
  void* args[] = {(void*)&Bmat, (void*)&bb_all, (void*)&seqb,
                  (void*)&hbuf0, (void*)&hbuf1, (void*)&ctr};
  hipError_t ce = hipLaunchCooperativeKernel((const void*)lstm_all, dim3(512),
                                             dim3(256), args, 0, stream);
  if (ce != hipSuccess) {
    (void)hipGetLastError();   // clear sticky error, fall back to per-step
    bf16_t* hb[2] = {hbuf0, hbuf1};
    for (int t = 0; t < T_N; ++t)
      lstm_step<<<512, 256, 0, stream>>>(Bmat, bb_all, seqb,
                                         hb[t & 1], hb[(t + 1) & 1], cbuf, t);
  }

  // h_95 lives in hbuf0 (t=95 odd writes hbuf0)
  out_gemm<<<dim3(16, 4), 256, 0, stream>>>(hbuf0, Woutb, bout, out);
}

// Round 6
// 2505.225 us; speedup vs baseline: 4.4393x; 4.4393x over previous
//
#include <hip/hip_runtime.h>
#include <hip/hip_bf16.h>
#include <stdint.h>

typedef __bf16 bf16_t;
typedef __attribute__((ext_vector_type(8))) __bf16 bf16x8;
typedef __attribute__((ext_vector_type(4))) float f32x4;

#define B_N 2048
#define T_N 96
#define I_N 64
#define H_N 1024
#define O_N 256
#define KTOT 1088   /* H + I */
#define NG   4096   /* 4*H  */

// ---------- helpers ----------
__device__ __forceinline__ void gload16(const void* g, void* l) {
  // global -> LDS direct, 16B per lane. LDS dest is wave-uniform base
  // (HW adds lane*16). Global source IS per-lane -> we pre-swizzle it.
  __builtin_amdgcn_global_load_lds(
      (const __attribute__((address_space(1))) uint32_t*)(uintptr_t)g,
      (__attribute__((address_space(3))) uint32_t*)(uintptr_t)l,
      16, 0, 0);
}

__device__ __forceinline__ float sigmoid_(float x) {
  return 1.0f / (1.0f + __expf(-x));
}
__device__ __forceinline__ float tanh_(float x) {
  float ax = fabsf(x);
  float e  = __expf(-2.0f * ax);     // (0,1], never overflows
  float t  = (1.0f - e) / (1.0f + e);
  return copysignf(t, x);
}

// ---------- prep kernels ----------
// Bmat row layout (unit-major-within-16): rr = by*128 + q, q = wc*64+g*16+lr
//   -> unit u = by*32 + wc*16 + lr, gate g. With this, MFMA fragment n (col
//   n*16+lr of a 64-col wave subtile) IS gate n of unit lr: the epilogue's
//   4 gates of one (row,unit) live in one lane's acc[m][0..3][e]. No LDS
//   exchange needed.
__global__ void prep_weights(const float* __restrict__ Wi_h, const float* __restrict__ Wf_h,
                             const float* __restrict__ Wm_h, const float* __restrict__ Wo_h,
                             const float* __restrict__ Wi_x, const float* __restrict__ Wf_x,
                             const float* __restrict__ Wm_x, const float* __restrict__ Wo_x,
                             bf16_t* __restrict__ Bmat) {
  int idx = blockIdx.x * blockDim.x + threadIdx.x;
  const int total = NG * KTOT;
  if (idx >= total) return;
  int rr = idx / KTOT;
  int k  = idx - rr * KTOT;
  int by = rr >> 7;
  int q  = rr & 127;
  int u  = by * 32 + ((q >> 6) << 4) + (q & 15);  // unit 0..1023
  int g  = (q >> 4) & 3;                          // 0:i 1:f 2:m 3:o
  const float* Wh[4] = {Wi_h, Wf_h, Wm_h, Wo_h};
  const float* Wx[4] = {Wi_x, Wf_x, Wm_x, Wo_x};
  float v = (k < H_N) ? Wh[g][u * H_N + k] : Wx[g][u * I_N + (k - H_N)];
  Bmat[idx] = (bf16_t)v;
}

// biases in plain concatenated order: bbI[g*1024 + u]
__global__ void prep_misc(const float* __restrict__ bi, const float* __restrict__ bf_,
                          const float* __restrict__ bm, const float* __restrict__ bo,
                          const float* __restrict__ Wout, float* __restrict__ bbI,
                          bf16_t* __restrict__ Wout_b) {
  int idx = blockIdx.x * blockDim.x + threadIdx.x;
  if (idx < NG) {
    int g = idx >> 10, u = idx & 1023;
    const float* bp[4] = {bi, bf_, bm, bo};
    bbI[idx] = bp[g][u];
  }
  if (idx < O_N * H_N) Wout_b[idx] = (bf16_t)Wout[idx];
}

__global__ void prep_seq(const float4* __restrict__ seq4, bf16_t* __restrict__ seqb,
                         bf16_t* __restrict__ h0, float* __restrict__ c0) {
  int idx = blockIdx.x * blockDim.x + threadIdx.x;
  const int n4 = (B_N * T_N * I_N) / 4;
  if (idx < n4) {
    float4 v = seq4[idx];
    union { bf16_t b[4]; uint2 u; } pk;
    pk.b[0] = (bf16_t)v.x; pk.b[1] = (bf16_t)v.y;
    pk.b[2] = (bf16_t)v.z; pk.b[3] = (bf16_t)v.w;
    *reinterpret_cast<uint2*>(seqb + (size_t)idx * 4) = pk.u;
  }
  if (idx < B_N * H_N) { h0[idx] = (bf16_t)0.0f; c0[idx] = 0.0f; }
}

// ---------- fused LSTM step (round-2 proven GEMM + in-register epilogue) ----
// Block: 128 batch rows x 128 gate cols (32 units x 4 gates). 256 thr,
// 2 blocks/CU. Double-buffered 2-phase K-loop, T2 source-pre-swizzle.
__global__ __launch_bounds__(256, 2) void lstm_step(
    const bf16_t* __restrict__ Bmat,   // [4H][KTOT], unit-major-within-16 rows
    const float*  __restrict__ bbI,    // [4][1024]
    const bf16_t* __restrict__ seqb,   // [B][T][I]
    const bf16_t* __restrict__ h_in,   // [B][H]
    bf16_t* __restrict__ h_out,        // [B][H]
    float*  __restrict__ c_buf,        // [B][H]
    int t) {
  // A bufs [0,16K)[16K,32K); B bufs [32K,48K)[48K,64K).
  __shared__ char smem[65536];

  const int tid  = threadIdx.x;
  const int wid  = tid >> 6;
  const int lane = tid & 63;

  // XCD-rect swizzle: 8 XCDs as 2x4 chunks of the 16x32 (bx,by) grid.
  const int bid = blockIdx.x;                 // 0..511
  const int xcd = bid & 7;
  const int r   = bid >> 3;                   // 0..63
  const int bx  = (xcd & 1) * 8 + (r & 7);    // 0..15 (M group)
  const int by  = (xcd >> 1) * 8 + (r >> 3);  // 0..31 (unit group)

  const int bm0   = bx * 128;                 // batch-row base
  const int n0    = by * 128;                 // Bmat row base
  const int jbase = by * 32;                  // unit base

  const int wr = wid >> 1, wc = wid & 1;      // wave covers 64x64 of 128x128
  const int lrow = lane & 15;

  f32x4 acc[4][4];
#pragma unroll
  for (int m = 0; m < 4; ++m)
#pragma unroll
    for (int n = 0; n < 4; ++n)
#pragma unroll
      for (int e = 0; e < 4; ++e) acc[m][n][e] = 0.0f;

  const int srow = tid >> 3;                     // 0..31
  const int cs   = ((tid & 7) ^ (srow & 7)) * 8; // swizzled source chunk

  auto stage = [&](int b, int s) {
    char* Ab = smem + b * 16384;
    char* Bb = smem + 32768 + b * 16384;
    if (s < 16) {
      const int k0 = s * 64;
#pragma unroll
      for (int it = 0; it < 4; ++it)
        gload16(h_in + (size_t)(bm0 + it * 32 + srow) * H_N + k0 + cs,
                Ab + it * 4096 + wid * 1024);
#pragma unroll
      for (int it = 0; it < 4; ++it)
        gload16(Bmat + (size_t)(n0 + it * 32 + srow) * KTOT + k0 + cs,
                Bb + it * 4096 + wid * 1024);
    } else {
#pragma unroll
      for (int it = 0; it < 4; ++it)
        gload16(seqb + (size_t)(bm0 + it * 32 + srow) * (T_N * I_N) + t * I_N + cs,
                Ab + it * 4096 + wid * 1024);
#pragma unroll
      for (int it = 0; it < 4; ++it)
        gload16(Bmat + (size_t)(n0 + it * 32 + srow) * KTOT + H_N + cs,
                Bb + it * 4096 + wid * 1024);
    }
  };

  stage(0, 0);
  __syncthreads();          // prologue: tile 0 ready

  int cur = 0;
  for (int kt = 0; kt < 17; ++kt) {
    if (kt < 16) stage(cur ^ 1, kt + 1);   // issue next-tile loads first

    const bf16_t* Abuf = (const bf16_t*)(smem + cur * 16384);
    const bf16_t* Bbuf = (const bf16_t*)(smem + 32768 + cur * 16384);
#pragma unroll
    for (int kh = 0; kh < 2; ++kh) {
      const int cc = (lane >> 4) + kh * 4;          // data chunk 0..7
      const int so = ((cc ^ (lrow & 7)) << 3);      // swizzled slot (elems)
      bf16x8 aq[4], bq[4];
#pragma unroll
      for (int m = 0; m < 4; ++m)
        aq[m] = *(const bf16x8*)(Abuf + (size_t)(wr * 64 + m * 16 + lrow) * 64 + so);
#pragma unroll
      for (int n = 0; n < 4; ++n)
        bq[n] = *(const bf16x8*)(Bbuf + (size_t)(wc * 64 + n * 16 + lrow) * 64 + so);
#pragma unroll
      for (int m = 0; m < 4; ++m)
#pragma unroll
        for (int n = 0; n < 4; ++n)
          acc[m][n] = __builtin_amdgcn_mfma_f32_16x16x32_bf16(aq[m], bq[n], acc[m][n], 0, 0, 0);
    }
    __syncthreads();   // next tile landed + all reads of cur done
    cur ^= 1;
  }

  // ---- in-register epilogue: acc[m][0..3][e] = (i,f,m,o) of one (row,unit)
  const int ub = jbase + wc * 16 + lrow;      // this lane's unit
  const float bi_ = bbI[0 * H_N + ub];
  const float bf_ = bbI[1 * H_N + ub];
  const float bm_ = bbI[2 * H_N + ub];
  const float bo_ = bbI[3 * H_N + ub];
  const int rbase = bm0 + wr * 64 + (lane >> 4) * 4;
#pragma unroll
  for (int m = 0; m < 4; ++m) {
#pragma unroll
    for (int e = 0; e < 4; ++e) {
      size_t gi = (size_t)(rbase + m * 16 + e) * H_N + ub;
      float i_ = sigmoid_(acc[m][0][e] + bi_);
      float f_ = sigmoid_(acc[m][1][e] + bf_);
      float g_ = tanh_(acc[m][2][e] + bm_);
      float o_ = sigmoid_(acc[m][3][e] + bo_);
      float cn = f_ * c_buf[gi] + i_ * g_;
      c_buf[gi] = cn;
      h_out[gi] = (bf16_t)(o_ * tanh_(cn));
    }
  }
}

// ---------- final projection: out = h_last @ Wout^T + bout ----------
__global__ __launch_bounds__(256, 2) void out_gemm(
    const bf16_t* __restrict__ h,     // [B][H]
    const bf16_t* __restrict__ Wb,    // [O][H]
    const float*  __restrict__ bout,  // [O]
    float* __restrict__ out) {        // [B][O]
  __shared__ char smem[16384 + 8192];
  bf16_t* A_lds = (bf16_t*)smem;            // [128][64]
  bf16_t* B_lds = (bf16_t*)(smem + 16384);  // [64][64]

  const int tid = threadIdx.x, wid = tid >> 6, lane = tid & 63;
  const int bm0 = blockIdx.x * 128;
  const int n0  = blockIdx.y * 64;
  const int wr = wid >> 1, wc = wid & 1;    // wave: 64 rows x 32 cols

  f32x4 acc[4][2];
#pragma unroll
  for (int m = 0; m < 4; ++m)
#pragma unroll
    for (int n = 0; n < 2; ++n)
#pragma unroll
      for (int e = 0; e < 4; ++e) acc[m][n][e] = 0.0f;

  const int srow = tid >> 3;
  const int scol = (tid & 7) * 8;

  for (int kt = 0; kt < 16; ++kt) {
    const int k0 = kt * 64;
#pragma unroll
    for (int it = 0; it < 4; ++it) {
      const bf16_t* gp = h + (size_t)(bm0 + it * 32 + srow) * H_N + k0 + scol;
      gload16(gp, (char*)A_lds + (size_t)(it * 2048 + wid * 512) * 2);
    }
#pragma unroll
    for (int it = 0; it < 2; ++it) {
      const bf16_t* gp = Wb + (size_t)(n0 + it * 32 + srow) * H_N + k0 + scol;
      gload16(gp, (char*)B_lds + (size_t)(it * 2048 + wid * 512) * 2);
    }
    __syncthreads();

    const int lrow = lane & 15;
#pragma unroll
    for (int kk = 0; kk < 64; kk += 32) {
      const int lk = (lane >> 4) * 8 + kk;
      bf16x8 aq[4], bq[2];
#pragma unroll
      for (int m = 0; m < 4; ++m)
        aq[m] = *(const bf16x8*)(A_lds + (size_t)(wr * 64 + m * 16 + lrow) * 64 + lk);
#pragma unroll
      for (int n = 0; n < 2; ++n)
        bq[n] = *(const bf16x8*)(B_lds + (size_t)(wc * 32 + n * 16 + lrow) * 64 + lk);
#pragma unroll
      for (int m = 0; m < 4; ++m)
#pragma unroll
        for (int n = 0; n < 2; ++n)
          acc[m][n] = __builtin_amdgcn_mfma_f32_16x16x32_bf16(aq[m], bq[n], acc[m][n], 0, 0, 0);
    }
    __syncthreads();
  }

#pragma unroll
  for (int m = 0; m < 4; ++m)
#pragma unroll
    for (int n = 0; n < 2; ++n)
#pragma unroll
      for (int e = 0; e < 4; ++e) {
        int row = bm0 + wr * 64 + m * 16 + (lane >> 4) * 4 + e;
        int col = n0 + wc * 32 + n * 16 + (lane & 15);
        out[(size_t)row * O_N + col] = acc[m][n][e] + bout[col];
      }
}

// ---------- launch ----------
extern "C" void kernel_launch(void* const* d_in, const int* in_sizes, int n_in,
                              void* d_out, int out_size, void* d_ws, size_t ws_size,
                              hipStream_t stream) {
  const float* seq  = (const float*)d_in[0];
  const float* Wf_x = (const float*)d_in[1];
  const float* bf_  = (const float*)d_in[2];
  const float* Wf_h = (const float*)d_in[3];
  const float* Wi_x = (const float*)d_in[4];
  const float* bi   = (const float*)d_in[5];
  const float* Wi_h = (const float*)d_in[6];
  const float* Wm_x = (const float*)d_in[7];
  const float* bm   = (const float*)d_in[8];
  const float* Wm_h = (const float*)d_in[9];
  const float* Wo_x = (const float*)d_in[10];
  const float* bo   = (const float*)d_in[11];
  const float* Wo_h = (const float*)d_in[12];
  const float* Wout = (const float*)d_in[13];
  const float* bout = (const float*)d_in[14];
  float* out = (float*)d_out;

  char* ws = (char*)d_ws;
  size_t off = 0;
  auto alloc = [&](size_t bytes) -> void* {
    void* p = ws + off;
    off = (off + bytes + 255) & ~(size_t)255;
    return p;
  };
  bf16_t* Bmat   = (bf16_t*)alloc((size_t)NG * KTOT * 2);       // 8.9 MB
  float*  bb_all = (float*) alloc((size_t)NG * 4);              // 16 KB
  bf16_t* Woutb  = (bf16_t*)alloc((size_t)O_N * H_N * 2);       // 512 KB
  bf16_t* seqb   = (bf16_t*)alloc((size_t)B_N * T_N * I_N * 2); // 24 MB
  bf16_t* hbuf0  = (bf16_t*)alloc((size_t)B_N * H_N * 2);       // 4 MB
  bf16_t* hbuf1  = (bf16_t*)alloc((size_t)B_N * H_N * 2);       // 4 MB
  float*  cbuf   = (float*) alloc((size_t)B_N * H_N * 4);       // 8 MB

  prep_weights<<<(NG * KTOT + 255) / 256, 256, 0, stream>>>(
      Wi_h, Wf_h, Wm_h, Wo_h, Wi_x, Wf_x, Wm_x, Wo_x, Bmat);
  prep_misc<<<(O_N * H_N + 255) / 256, 256, 0, stream>>>(
      bi, bf_, bm, bo, Wout, bb_all, Woutb);
  prep_seq<<<((B_N * T_N * I_N / 4) + 255) / 256, 256, 0, stream>>>(
      (const float4*)seq, seqb, hbuf0, cbuf);

  bf16_t* hb[2] = {hbuf0, hbuf1};
  for (int t = 0; t < T_N; ++t) {
    lstm_step<<<512, 256, 0, stream>>>(Bmat, bb_all, seqb,
                                       hb[t & 1], hb[(t + 1) & 1], cbuf, t);
  }
  // after t=95 the freshest h is in hbuf0
  out_gemm<<<dim3(16, 4), 256, 0, stream>>>(hbuf0, Woutb, bout, out);
}

// Round 7
// 2302.982 us; speedup vs baseline: 4.8292x; 1.0878x over previous
//
#include <hip/hip_runtime.h>
#include <hip/hip_bf16.h>
#include <stdint.h>

typedef __bf16 bf16_t;
typedef __attribute__((ext_vector_type(8))) __bf16 bf16x8;
typedef __attribute__((ext_vector_type(4))) float f32x4;

#define B_N 2048
#define T_N 96
#define I_N 64
#define H_N 1024
#define O_N 256
#define KTOT 1088   /* H + I */
#define NG   4096   /* 4*H  */

// ---------- helpers ----------
__device__ __forceinline__ void gload16(const void* g, void* l) {
  // global -> LDS direct, 16B per lane. LDS dest is wave-uniform base
  // (HW adds lane*16). Global source IS per-lane -> we pre-swizzle it.
  __builtin_amdgcn_global_load_lds(
      (const __attribute__((address_space(1))) uint32_t*)(uintptr_t)g,
      (__attribute__((address_space(3))) uint32_t*)(uintptr_t)l,
      16, 0, 0);
}

__device__ __forceinline__ float sigmoid_(float x) {
  return 1.0f / (1.0f + __expf(-x));
}
__device__ __forceinline__ float tanh_(float x) {
  float ax = fabsf(x);
  float e  = __expf(-2.0f * ax);     // (0,1], never overflows
  float t  = (1.0f - e) / (1.0f + e);
  return copysignf(t, x);
}

// ---------- prep kernels ----------
// Bmat row layout for BN=256 blocks: rr = by*256 + q, q = wcq*64 + g*16 + lr
//   -> unit u = by*64 + wcq*16 + lr, gate g. MFMA fragment n of wave wcq IS
//   gate n of unit (by*64 + wcq*16 + lrow): gates live in one lane's
//   acc[m][0..3][e] -> fully in-register epilogue (verified round 6).
__global__ void prep_weights(const float* __restrict__ Wi_h, const float* __restrict__ Wf_h,
                             const float* __restrict__ Wm_h, const float* __restrict__ Wo_h,
                             const float* __restrict__ Wi_x, const float* __restrict__ Wf_x,
                             const float* __restrict__ Wm_x, const float* __restrict__ Wo_x,
                             bf16_t* __restrict__ Bmat) {
  int idx = blockIdx.x * blockDim.x + threadIdx.x;
  const int total = NG * KTOT;
  if (idx >= total) return;
  int rr = idx / KTOT;
  int k  = idx - rr * KTOT;
  int by  = rr >> 8;                               // 0..15
  int q   = rr & 255;
  int wcq = q >> 6;                                // 0..3
  int g   = (q >> 4) & 3;                          // 0:i 1:f 2:m 3:o
  int lr  = q & 15;
  int u   = by * 64 + wcq * 16 + lr;               // unit 0..1023
  const float* Wh[4] = {Wi_h, Wf_h, Wm_h, Wo_h};
  const float* Wx[4] = {Wi_x, Wf_x, Wm_x, Wo_x};
  float v = (k < H_N) ? Wh[g][u * H_N + k] : Wx[g][u * I_N + (k - H_N)];
  Bmat[idx] = (bf16_t)v;
}

// biases in plain concatenated order: bbI[g*1024 + u]
__global__ void prep_misc(const float* __restrict__ bi, const float* __restrict__ bf_,
                          const float* __restrict__ bm, const float* __restrict__ bo,
                          const float* __restrict__ Wout, float* __restrict__ bbI,
                          bf16_t* __restrict__ Wout_b) {
  int idx = blockIdx.x * blockDim.x + threadIdx.x;
  if (idx < NG) {
    int g = idx >> 10, u = idx & 1023;
    const float* bp[4] = {bi, bf_, bm, bo};
    bbI[idx] = bp[g][u];
  }
  if (idx < O_N * H_N) Wout_b[idx] = (bf16_t)Wout[idx];
}

__global__ void prep_seq(const float4* __restrict__ seq4, bf16_t* __restrict__ seqb,
                         bf16_t* __restrict__ h0, float* __restrict__ c0) {
  int idx = blockIdx.x * blockDim.x + threadIdx.x;
  const int n4 = (B_N * T_N * I_N) / 4;
  if (idx < n4) {
    float4 v = seq4[idx];
    union { bf16_t b[4]; uint2 u; } pk;
    pk.b[0] = (bf16_t)v.x; pk.b[1] = (bf16_t)v.y;
    pk.b[2] = (bf16_t)v.z; pk.b[3] = (bf16_t)v.w;
    *reinterpret_cast<uint2*>(seqb + (size_t)idx * 4) = pk.u;
  }
  if (idx < B_N * H_N) { h0[idx] = (bf16_t)0.0f; c0[idx] = 0.0f; }
}

// ---------- fused LSTM step: counted-vmcnt fine-phase pipeline ----------
// Tile 128(M) x 256(N), BK=64, 512 thr = 8 waves (2M x 4N, 64x64 each).
// 3 LDS buffers (A 16K + B 32K = 48K each; 144 KB total, 1 block/CU).
// Steady state: 12 loads in flight (tiles kt+1, kt+2); vmcnt(6) per tile,
// vmcnt(0) only at the tail. Raw s_barrier (no implicit drain). Per tile:
// 2 phases {8 ds_read || 3 gload_lds of kt+2 -> setprio MFMA x16}.
__global__ __launch_bounds__(512, 1) void lstm_step(
    const bf16_t* __restrict__ Bmat,   // [4H][KTOT], layout per prep_weights
    const float*  __restrict__ bbI,    // [4][1024]
    const bf16_t* __restrict__ seqb,   // [B][T][I]
    const bf16_t* __restrict__ h_in,   // [B][H]
    bf16_t* __restrict__ h_out,        // [B][H]
    float*  __restrict__ c_buf,        // [B][H]
    int t) {
  __shared__ char smem[147456];        // 3 x (16384 A + 32768 B)

  const int tid  = threadIdx.x;
  const int wid  = tid >> 6;
  const int lane = tid & 63;

  // XCD-rect swizzle on the 16x16 (bx,by) grid: each XCD an 8x4 rect.
  const int bid = blockIdx.x;                 // 0..255
  const int xcd = bid & 7;
  const int r   = bid >> 3;                   // 0..31
  const int bx  = (xcd & 1) * 8 + (r & 7);    // 0..15 (M group)
  const int by  = (xcd >> 1) * 4 + (r >> 3);  // 0..15 (N group)

  const int bm0  = bx * 128;                  // batch-row base
  const int n0   = by * 256;                  // Bmat row base
  const int jb64 = by * 64;                   // unit base

  const int wr = wid >> 2, wc = wid & 3;      // 2M x 4N waves
  const int lrow = lane & 15;

  const int srow = tid >> 3;                     // 0..63
  const int cs   = ((tid & 7) ^ (srow & 7)) * 8; // swizzled source chunk

  f32x4 acc[4][4];
#pragma unroll
  for (int m = 0; m < 4; ++m)
#pragma unroll
    for (int n = 0; n < 4; ++n)
#pragma unroll
      for (int e = 0; e < 4; ++e) acc[m][n][e] = 0.0f;

  // stage pieces: A = 2 gloads, B = 1 + 3 gloads (6 per tile per wave)
  auto stageA = [&](int b, int s) {
    char* Ab = smem + b * 49152;
    if (s < 16) {
      const int k0 = s * 64;
#pragma unroll
      for (int it = 0; it < 2; ++it)
        gload16(h_in + (size_t)(bm0 + it * 64 + srow) * H_N + k0 + cs,
                Ab + it * 8192 + wid * 1024);
    } else {
#pragma unroll
      for (int it = 0; it < 2; ++it)
        gload16(seqb + (size_t)(bm0 + it * 64 + srow) * (T_N * I_N) + t * I_N + cs,
                Ab + it * 8192 + wid * 1024);
    }
  };
  auto stageB0 = [&](int b, int s) {
    char* Bb = smem + b * 49152 + 16384;
    const int k0 = (s < 16) ? s * 64 : H_N;
    gload16(Bmat + (size_t)(n0 + srow) * KTOT + k0 + cs, Bb + wid * 1024);
  };
  auto stageB13 = [&](int b, int s) {
    char* Bb = smem + b * 49152 + 16384;
    const int k0 = (s < 16) ? s * 64 : H_N;
#pragma unroll
    for (int it = 1; it < 4; ++it)
      gload16(Bmat + (size_t)(n0 + it * 64 + srow) * KTOT + k0 + cs,
              Bb + it * 8192 + wid * 1024);
  };

  // prologue: tiles 0 and 1 fully issued (12 loads in flight)
  stageA(0, 0); stageB0(0, 0); stageB13(0, 0);
  stageA(1, 1); stageB0(1, 1); stageB13(1, 1);

#pragma unroll 1
  for (int kt = 0; kt < 17; ++kt) {
    // wait tile kt's 6 loads (leave kt+1's flying); drain only at tail
    if (kt < 16) { asm volatile("s_waitcnt vmcnt(6)" ::: "memory"); }
    else         { asm volatile("s_waitcnt vmcnt(0)" ::: "memory"); }
    __builtin_amdgcn_sched_barrier(0);
    __builtin_amdgcn_s_barrier();       // all waves: tile kt landed; reads of
    __builtin_amdgcn_sched_barrier(0);  // tile kt-1 (buffer (kt+2)%3) done

    const bf16_t* Abuf = (const bf16_t*)(smem + (kt % 3) * 49152);
    const bf16_t* Bbuf = (const bf16_t*)(smem + (kt % 3) * 49152 + 16384);
    const int b2 = (kt + 2) % 3;
    const bool do_stage = (kt + 2 <= 16);

    // ---- phase 0 (kh=0) ----
    {
      const int cc = (lane >> 4);
      const int so = ((cc ^ (lrow & 7)) << 3);
      bf16x8 aq[4], bq[4];
#pragma unroll
      for (int m = 0; m < 4; ++m)
        aq[m] = *(const bf16x8*)(Abuf + (size_t)(wr * 64 + m * 16 + lrow) * 64 + so);
#pragma unroll
      for (int n = 0; n < 4; ++n)
        bq[n] = *(const bf16x8*)(Bbuf + (size_t)(wc * 64 + n * 16 + lrow) * 64 + so);
      if (do_stage) { stageA(b2, kt + 2); stageB0(b2, kt + 2); }
      __builtin_amdgcn_s_setprio(1);
#pragma unroll
      for (int m = 0; m < 4; ++m)
#pragma unroll
        for (int n = 0; n < 4; ++n)
          acc[m][n] = __builtin_amdgcn_mfma_f32_16x16x32_bf16(aq[m], bq[n], acc[m][n], 0, 0, 0);
      __builtin_amdgcn_s_setprio(0);
      __builtin_amdgcn_sched_barrier(0);
    }
    // ---- phase 1 (kh=1) ----
    {
      const int cc = (lane >> 4) + 4;
      const int so = ((cc ^ (lrow & 7)) << 3);
      bf16x8 aq[4], bq[4];
#pragma unroll
      for (int m = 0; m < 4; ++m)
        aq[m] = *(const bf16x8*)(Abuf + (size_t)(wr * 64 + m * 16 + lrow) * 64 + so);
#pragma unroll
      for (int n = 0; n < 4; ++n)
        bq[n] = *(const bf16x8*)(Bbuf + (size_t)(wc * 64 + n * 16 + lrow) * 64 + so);
      if (do_stage) stageB13(b2, kt + 2);
      __builtin_amdgcn_s_setprio(1);
#pragma unroll
      for (int m = 0; m < 4; ++m)
#pragma unroll
        for (int n = 0; n < 4; ++n)
          acc[m][n] = __builtin_amdgcn_mfma_f32_16x16x32_bf16(aq[m], bq[n], acc[m][n], 0, 0, 0);
      __builtin_amdgcn_s_setprio(0);
      __builtin_amdgcn_sched_barrier(0);
    }
  }

  // ---- in-register epilogue: acc[m][0..3][e] = (i,f,m,o) of one (row,unit)
  const int ub = jb64 + wc * 16 + lrow;       // this lane's unit
  const float bi_ = bbI[0 * H_N + ub];
  const float bf_ = bbI[1 * H_N + ub];
  const float bm_ = bbI[2 * H_N + ub];
  const float bo_ = bbI[3 * H_N + ub];
  const int rbase = bm0 + wr * 64 + (lane >> 4) * 4;
#pragma unroll
  for (int m = 0; m < 4; ++m) {
#pragma unroll
    for (int e = 0; e < 4; ++e) {
      size_t gi = (size_t)(rbase + m * 16 + e) * H_N + ub;
      float i_ = sigmoid_(acc[m][0][e] + bi_);
      float f_ = sigmoid_(acc[m][1][e] + bf_);
      float g_ = tanh_(acc[m][2][e] + bm_);
      float o_ = sigmoid_(acc[m][3][e] + bo_);
      float cn = f_ * c_buf[gi] + i_ * g_;
      c_buf[gi] = cn;
      h_out[gi] = (bf16_t)(o_ * tanh_(cn));
    }
  }
}

// ---------- final projection: out = h_last @ Wout^T + bout ----------
__global__ __launch_bounds__(256, 2) void out_gemm(
    const bf16_t* __restrict__ h,     // [B][H]
    const bf16_t* __restrict__ Wb,    // [O][H]
    const float*  __restrict__ bout,  // [O]
    float* __restrict__ out) {        // [B][O]
  __shared__ char smem[16384 + 8192];
  bf16_t* A_lds = (bf16_t*)smem;            // [128][64]
  bf16_t* B_lds = (bf16_t*)(smem + 16384);  // [64][64]

  const int tid = threadIdx.x, wid = tid >> 6, lane = tid & 63;
  const int bm0 = blockIdx.x * 128;
  const int n0  = blockIdx.y * 64;
  const int wr = wid >> 1, wc = wid & 1;    // wave: 64 rows x 32 cols

  f32x4 acc[4][2];
#pragma unroll
  for (int m = 0; m < 4; ++m)
#pragma unroll
    for (int n = 0; n < 2; ++n)
#pragma unroll
      for (int e = 0; e < 4; ++e) acc[m][n][e] = 0.0f;

  const int srow = tid >> 3;
  const int scol = (tid & 7) * 8;

  for (int kt = 0; kt < 16; ++kt) {
    const int k0 = kt * 64;
#pragma unroll
    for (int it = 0; it < 4; ++it) {
      const bf16_t* gp = h + (size_t)(bm0 + it * 32 + srow) * H_N + k0 + scol;
      gload16(gp, (char*)A_lds + (size_t)(it * 2048 + wid * 512) * 2);
    }
#pragma unroll
    for (int it = 0; it < 2; ++it) {
      const bf16_t* gp = Wb + (size_t)(n0 + it * 32 + srow) * H_N + k0 + scol;
      gload16(gp, (char*)B_lds + (size_t)(it * 2048 + wid * 512) * 2);
    }
    __syncthreads();

    const int lrow = lane & 15;
#pragma unroll
    for (int kk = 0; kk < 64; kk += 32) {
      const int lk = (lane >> 4) * 8 + kk;
      bf16x8 aq[4], bq[2];
#pragma unroll
      for (int m = 0; m < 4; ++m)
        aq[m] = *(const bf16x8*)(A_lds + (size_t)(wr * 64 + m * 16 + lrow) * 64 + lk);
#pragma unroll
      for (int n = 0; n < 2; ++n)
        bq[n] = *(const bf16x8*)(B_lds + (size_t)(wc * 32 + n * 16 + lrow) * 64 + lk);
#pragma unroll
      for (int m = 0; m < 4; ++m)
#pragma unroll
        for (int n = 0; n < 2; ++n)
          acc[m][n] = __builtin_amdgcn_mfma_f32_16x16x32_bf16(aq[m], bq[n], acc[m][n], 0, 0, 0);
    }
    __syncthreads();
  }

#pragma unroll
  for (int m = 0; m < 4; ++m)
#pragma unroll
    for (int n = 0; n < 2; ++n)
#pragma unroll
      for (int e = 0; e < 4; ++e) {
        int row = bm0 + wr * 64 + m * 16 + (lane >> 4) * 4 + e;
        int col = n0 + wc * 32 + n * 16 + (lane & 15);
        out[(size_t)row * O_N + col] = acc[m][n][e] + bout[col];
      }
}

// ---------- launch ----------
extern "C" void kernel_launch(void* const* d_in, const int* in_sizes, int n_in,
                              void* d_out, int out_size, void* d_ws, size_t ws_size,
                              hipStream_t stream) {
  const float* seq  = (const float*)d_in[0];
  const float* Wf_x = (const float*)d_in[1];
  const float* bf_  = (const float*)d_in[2];
  const float* Wf_h = (const float*)d_in[3];
  const float* Wi_x = (const float*)d_in[4];
  const float* bi   = (const float*)d_in[5];
  const float* Wi_h = (const float*)d_in[6];
  const float* Wm_x = (const float*)d_in[7];
  const float* bm   = (const float*)d_in[8];
  const float* Wm_h = (const float*)d_in[9];
  const float* Wo_x = (const float*)d_in[10];
  const float* bo   = (const float*)d_in[11];
  const float* Wo_h = (const float*)d_in[12];
  const float* Wout = (const float*)d_in[13];
  const float* bout = (const float*)d_in[14];
  float* out = (float*)d_out;

  char* ws = (char*)d_ws;
  size_t off = 0;
  auto alloc = [&](size_t bytes) -> void* {
    void* p = ws + off;
    off = (off + bytes + 255) & ~(size_t)255;
    return p;
  };
  bf16_t* Bmat   = (bf16_t*)alloc((size_t)NG * KTOT * 2);       // 8.9 MB
  float*  bb_all = (float*) alloc((size_t)NG * 4);              // 16 KB
  bf16_t* Woutb  = (bf16_t*)alloc((size_t)O_N * H_N * 2);       // 512 KB
  bf16_t* seqb   = (bf16_t*)alloc((size_t)B_N * T_N * I_N * 2); // 24 MB
  bf16_t* hbuf0  = (bf16_t*)alloc((size_t)B_N * H_N * 2);       // 4 MB
  bf16_t* hbuf1  = (bf16_t*)alloc((size_t)B_N * H_N * 2);       // 4 MB
  float*  cbuf   = (float*) alloc((size_t)B_N * H_N * 4);       // 8 MB

  prep_weights<<<(NG * KTOT + 255) / 256, 256, 0, stream>>>(
      Wi_h, Wf_h, Wm_h, Wo_h, Wi_x, Wf_x, Wm_x, Wo_x, Bmat);
  prep_misc<<<(O_N * H_N + 255) / 256, 256, 0, stream>>>(
      bi, bf_, bm, bo, Wout, bb_all, Woutb);
  prep_seq<<<((B_N * T_N * I_N / 4) + 255) / 256, 256, 0, stream>>>(
      (const float4*)seq, seqb, hbuf0, cbuf);

  bf16_t* hb[2] = {hbuf0, hbuf1};
  for (int t = 0; t < T_N; ++t) {
    lstm_step<<<256, 512, 0, stream>>>(Bmat, bb_all, seqb,
                                       hb[t & 1], hb[(t + 1) & 1], cbuf, t);
  }
  // after t=95 the freshest h is in hbuf0
  out_gemm<<<dim3(16, 4), 256, 0, stream>>>(hbuf0, Woutb, bout, out);
}